// Round 1
// baseline (431.155 us; speedup 1.0000x reference)
//
#include <hip/hip_runtime.h>
#include <cmath>

#define BB 16
#define CC 64
#define PP 16384   // H*W = 128*128
#define DIMF 256

// ---------------------------------------------------------------------------
// Kernel 1: channel means of the 4 tensors -> cf[B][4][C]
// grid = B*C blocks, 256 threads. Each block reduces four 64 KiB planes.
// ---------------------------------------------------------------------------
__global__ __launch_bounds__(256) void k_means(const float* __restrict__ low,
                                               const float* __restrict__ high,
                                               const float* __restrict__ flow,
                                               const float* __restrict__ fb,
                                               float* __restrict__ cf) {
    int bc = blockIdx.x;            // b*64 + c
    int b = bc >> 6, c = bc & 63;
    int tid = threadIdx.x;
    size_t base = (size_t)bc * PP;
    const float* in[4] = {low, high, flow, fb};
    __shared__ float red[256];
    for (int t = 0; t < 4; ++t) {
        const float4* p = (const float4*)(in[t] + base);
        float s = 0.f;
        #pragma unroll 4
        for (int i = tid; i < PP / 4; i += 256) {
            float4 v = p[i];
            s += (v.x + v.y) + (v.z + v.w);
        }
        red[tid] = s;
        __syncthreads();
        for (int off = 128; off > 0; off >>= 1) {
            if (tid < off) red[tid] += red[tid + off];
            __syncthreads();
        }
        if (tid == 0) cf[(b * 4 + t) * CC + c] = red[0] * (1.0f / PP);
        __syncthreads();
    }
}

// ---------------------------------------------------------------------------
// Kernel 2: adjacency + GCN + 4 SE heads + effective mixing matrices.
// grid = B blocks, 256 threads. Output: Amat[b][t][c][o] (o contiguous).
// ---------------------------------------------------------------------------
__global__ __launch_bounds__(256) void k_small(const float* __restrict__ cf,
    const float* __restrict__ Wgcn, const float* __restrict__ bgcn,
    const float* __restrict__ W1, const float* __restrict__ b1,
    const float* __restrict__ W2, const float* __restrict__ b2,
    const float* __restrict__ W3, const float* __restrict__ b3,
    const float* __restrict__ W4, const float* __restrict__ b4,
    const float* __restrict__ Wgate,
    float* __restrict__ Amat) {
    int b = blockIdx.x;
    int tid = threadIdx.x;
    __shared__ float x[4][64];
    __shared__ float nrm[4];
    __shared__ float adj[16];
    __shared__ float y[4][64];
    __shared__ float fc[256];
    __shared__ float e[4][64];

    x[tid >> 6][tid & 63] = cf[b * 256 + tid];
    __syncthreads();

    if (tid < 4) {
        float s = 0.f;
        for (int c = 0; c < 64; ++c) s += x[tid][c] * x[tid][c];
        nrm[tid] = sqrtf(s);
    }
    __syncthreads();

    if (tid < 16) {
        int i = tid >> 2, j = tid & 3;
        float s = 0.f;
        for (int c = 0; c < 64; ++c) s += x[i][c] * x[j][c];
        adj[tid] = s / (nrm[i] * nrm[j]);
    }
    __syncthreads();

    {   // y = adj @ x   [4][64]
        int i = tid >> 6, c = tid & 63;
        float s = 0.f;
        for (int j = 0; j < 4; ++j) s += adj[i * 4 + j] * x[j][c];
        y[i][c] = s;
    }
    __syncthreads();

    {   // h = relu(y @ Wgcn + bgcn) -> fc flattened [256]
        int i = tid >> 6, d = tid & 63;
        float s = bgcn[d];
        for (int c = 0; c < 64; ++c) s += y[i][c] * Wgcn[c * 64 + d];
        fc[i * 64 + d] = fmaxf(s, 0.f);
    }
    __syncthreads();

    {   // e_k = sigmoid(fc @ Wk^T + bk), k = 0..3
        int k = tid >> 6, c = tid & 63;
        const float* Wk = (k == 0) ? W1 : (k == 1) ? W2 : (k == 2) ? W3 : W4;
        const float* bk = (k == 0) ? b1 : (k == 1) ? b2 : (k == 2) ? b3 : b4;
        float s = bk[c];
        for (int d = 0; d < 256; ++d) s += fc[d] * Wk[c * 256 + d];
        e[k][c] = 1.f / (1.f + expf(-s));
    }
    __syncthreads();

    // Effective mixing matrices:
    // A[t][c][o] = Wg[o, t*64+c] + e[t][c] * (sum_q Wg[o, q*64+c] - Wg[o, t*64+c])
    float* Ab = Amat + b * 4 * 64 * 64;
    for (int ii = tid; ii < 4 * 64 * 64; ii += 256) {
        int t = ii >> 12, c = (ii >> 6) & 63, o = ii & 63;
        float w0 = Wgate[o * 256 + 0   + c];
        float w1 = Wgate[o * 256 + 64  + c];
        float w2 = Wgate[o * 256 + 128 + c];
        float w3 = Wgate[o * 256 + 192 + c];
        float wt = (t == 0) ? w0 : (t == 1) ? w1 : (t == 2) ? w2 : w3;
        float sum = (w0 + w1) + (w2 + w3);
        Ab[ii] = wt + e[t][c] * (sum - wt);
    }
}

// ---------------------------------------------------------------------------
// Kernel 3: out[b,o,p] = sum_t sum_c A[b][t][c][o] * x_t[b,c,p] + bgate[o]
// grid = B*64 blocks (256 pixels/tile), 256 threads.
// Thread: 16 outs (o-group = wave id) x 4 pixels (float4). A loads are
// wave-uniform -> scalar path; x loads coalesced float4.
// ---------------------------------------------------------------------------
__global__ __launch_bounds__(256) void k_gemm(const float* __restrict__ low,
    const float* __restrict__ high, const float* __restrict__ flow,
    const float* __restrict__ fb, const float* __restrict__ Amat,
    const float* __restrict__ bgate, float* __restrict__ out) {
    int blk = blockIdx.x;
    int b = blk >> 6;
    int tile = blk & 63;
    int tid = threadIdx.x;
    int pt = tid & 63;
    int og = __builtin_amdgcn_readfirstlane(tid >> 6);   // wave-uniform out-group
    int p0 = tile * 256 + pt * 4;

    const float* in[4] = {low, high, flow, fb};
    float acc[16][4];
    #pragma unroll
    for (int j = 0; j < 16; ++j)
        #pragma unroll
        for (int q = 0; q < 4; ++q) acc[j][q] = 0.f;

    const float* Ab = Amat + b * 16384 + og * 16;   // [b][t][c][o], o contig
    #pragma unroll 1
    for (int t = 0; t < 4; ++t) {
        const float* xp = in[t] + (size_t)b * CC * PP + p0;
        const float* Ap = Ab + t * 4096;
        #pragma unroll 2
        for (int c = 0; c < 64; ++c) {
            float4 xv = *(const float4*)(xp + (size_t)c * PP);
            const float* Ar = Ap + c * 64;
            #pragma unroll
            for (int j = 0; j < 16; ++j) {
                float a = Ar[j];
                acc[j][0] = fmaf(a, xv.x, acc[j][0]);
                acc[j][1] = fmaf(a, xv.y, acc[j][1]);
                acc[j][2] = fmaf(a, xv.z, acc[j][2]);
                acc[j][3] = fmaf(a, xv.w, acc[j][3]);
            }
        }
    }

    #pragma unroll
    for (int j = 0; j < 16; ++j) {
        int o = og * 16 + j;
        float bg = bgate[o];
        float4 r = make_float4(acc[j][0] + bg, acc[j][1] + bg,
                               acc[j][2] + bg, acc[j][3] + bg);
        *(float4*)(out + ((size_t)(b * CC + o)) * PP + p0) = r;
    }
}

extern "C" void kernel_launch(void* const* d_in, const int* in_sizes, int n_in,
                              void* d_out, int out_size, void* d_ws, size_t ws_size,
                              hipStream_t stream) {
    const float* low  = (const float*)d_in[0];
    const float* high = (const float*)d_in[1];
    const float* flow = (const float*)d_in[2];
    const float* fb   = (const float*)d_in[3];
    const float* Wgcn = (const float*)d_in[4];
    const float* bgcn = (const float*)d_in[5];
    const float* W1   = (const float*)d_in[6];
    const float* b1   = (const float*)d_in[7];
    const float* W2   = (const float*)d_in[8];
    const float* b2   = (const float*)d_in[9];
    const float* W3   = (const float*)d_in[10];
    const float* b3   = (const float*)d_in[11];
    const float* W4   = (const float*)d_in[12];
    const float* b4   = (const float*)d_in[13];
    const float* Wgate = (const float*)d_in[14];
    const float* bgate = (const float*)d_in[15];
    float* out = (float*)d_out;

    float* cf   = (float*)d_ws;          // [16][4][64]   = 4096 floats
    float* Amat = (float*)d_ws + 4096;   // [16][4][64][64] = 65536 floats

    k_means<<<BB * CC, 256, 0, stream>>>(low, high, flow, fb, cf);
    k_small<<<BB, 256, 0, stream>>>(cf, Wgcn, bgcn, W1, b1, W2, b2, W3, b3,
                                    W4, b4, Wgate, Amat);
    k_gemm<<<BB * CC, 256, 0, stream>>>(low, high, flow, fb, Amat, bgate, out);
}